// Round 1
// baseline (3497.314 us; speedup 1.0000x reference)
//
#include <hip/hip_runtime.h>
#include <hip/hip_bf16.h>
#include <stdint.h>

// Problem constants
#define BB 4
#define SS 2048
#define HIDD 768
#define HH 12
#define DD 64
#define SCALE_F 0.125f

using bf16 = __hip_bfloat16;

// ---------- load/store helpers (dtype-generic) ----------
__device__ __forceinline__ float ldf(const float* p, size_t i) { return p[i]; }
__device__ __forceinline__ float ldf(const bf16* p, size_t i) { return __bfloat162float(p[i]); }
__device__ __forceinline__ void stf(float* p, size_t i, float v) { p[i] = v; }
__device__ __forceinline__ void stf(bf16* p, size_t i, float v) { p[i] = __float2bfloat16(v); }

// ---------- dtype detector ----------
// flags[0]: 0 = float inputs/outputs are fp32, 1 = bf16
// flags[1]: 0 = mask is int32, 1 = mask is 1-byte
__global__ void detect_kernel(const uint32_t* __restrict__ qraw,
                              const uint32_t* __restrict__ mraw,
                              int* __restrict__ flags) {
    __shared__ int ci, cn;
    int tid = threadIdx.x;
    if (tid == 0) { ci = 0; cn = 0; }
    __syncthreads();
    int li = 0;
    for (int l = 0; l < 8; l++) {
        uint32_t w = qraw[tid + l * 256];
        #pragma unroll
        for (int h = 0; h < 2; h++) {
            uint32_t bits = (h ? (w >> 16) : (w & 0xffffu)) << 16;
            float f = __uint_as_float(bits);
            float a = fabsf(f);
            // true-bf16 N(0,1) data: essentially never outside [1e-4, 1e3]
            if (a != 0.0f && (a > 1e3f || a < 1e-4f)) li++;
        }
    }
    int ln = 0;
    for (int l = 0; l < 4; l++) {
        if (mraw[tid + l * 256] > 1u) ln++;
    }
    atomicAdd(&ci, li);
    atomicAdd(&cn, ln);
    __syncthreads();
    if (tid == 0) {
        flags[0] = (ci > 1024) ? 0 : 1;  // many insane halves -> fp32
        flags[1] = (cn > 64) ? 1 : 0;    // many non-{0,1} words -> byte mask
    }
}

// ---------- projection GEMM: Y = X @ W + b, store head-split bf16 [B,H,S,D] ----------
// X: [B*S, 768] (T), W: [768,768] (T), bias: [768] (T) -> Yh bf16 [B,H,S,D]
template <typename T>
__global__ __launch_bounds__(256) void proj_kernel(const int* __restrict__ flags, int want,
                                                   const T* __restrict__ X,
                                                   const T* __restrict__ W,
                                                   const T* __restrict__ bias,
                                                   bf16* __restrict__ Yh) {
    if (flags[0] != want) return;
    __shared__ float xs[64][17];
    __shared__ float wsm[16][65];
    int tid = threadIdx.x;
    int row0 = blockIdx.y * 64;
    int col0 = blockIdx.x * 64;
    int tx = tid & 15, ty = tid >> 4;
    float acc[4][4] = {};
    for (int kt = 0; kt < HIDD; kt += 16) {
        #pragma unroll
        for (int l = 0; l < 4; l++) {
            int idx = tid + l * 256;
            int rr = idx >> 4, kk = idx & 15;
            xs[rr][kk] = ldf(X, (size_t)(row0 + rr) * HIDD + kt + kk);
        }
        #pragma unroll
        for (int l = 0; l < 4; l++) {
            int idx = tid + l * 256;
            int kk = idx >> 6, cc = idx & 63;
            wsm[kk][cc] = ldf(W, (size_t)(kt + kk) * HIDD + col0 + cc);
        }
        __syncthreads();
        #pragma unroll
        for (int kk = 0; kk < 16; kk++) {
            float a[4], b[4];
            #pragma unroll
            for (int i = 0; i < 4; i++) a[i] = xs[ty * 4 + i][kk];
            #pragma unroll
            for (int j = 0; j < 4; j++) b[j] = wsm[kk][tx * 4 + j];
            #pragma unroll
            for (int i = 0; i < 4; i++)
                #pragma unroll
                for (int j = 0; j < 4; j++) acc[i][j] += a[i] * b[j];
        }
        __syncthreads();
    }
    #pragma unroll
    for (int i = 0; i < 4; i++) {
        int r = row0 + ty * 4 + i;
        int b_ = r >> 11, s = r & 2047;
        #pragma unroll
        for (int j = 0; j < 4; j++) {
            int c = col0 + tx * 4 + j;
            float v = acc[i][j] + ldf(bias, (size_t)c);
            int h = c >> 6, d = c & 63;
            Yh[(((size_t)b_ * HH + h) * SS + s) * DD + d] = __float2bfloat16(v);
        }
    }
}

// ---------- scores: S = mask ? -1e9 : scale * q.k, write raw scores to P region ----------
template <typename T>
__global__ __launch_bounds__(256) void scores_kernel(const int* __restrict__ flags, int want,
                                                     const bf16* __restrict__ qh,
                                                     const bf16* __restrict__ kh,
                                                     const void* __restrict__ maskp,
                                                     T* __restrict__ P) {
    if (flags[0] != want) return;
    int maskByte = flags[1];
    __shared__ float qs[64][65];
    __shared__ float ks[64][65];
    int tid = threadIdx.x;
    int q0 = blockIdx.x * 64;
    int bh = blockIdx.y;
    int b_ = bh / HH;
    int tx = tid & 15, ty = tid >> 4;
    const bf16* qbase = qh + ((size_t)bh * SS + q0) * DD;
    #pragma unroll
    for (int l = 0; l < 16; l++) {
        int idx = tid + l * 256;
        int rr = idx >> 6, dd = idx & 63;
        qs[rr][dd] = __bfloat162float(qbase[rr * 64 + dd]);
    }
    const int* mi = (const int*)maskp;
    const uint8_t* mb = (const uint8_t*)maskp;
    for (int kt = 0; kt < SS; kt += 64) {
        const bf16* kbase = kh + ((size_t)bh * SS + kt) * DD;
        #pragma unroll
        for (int l = 0; l < 16; l++) {
            int idx = tid + l * 256;
            int rr = idx >> 6, dd = idx & 63;
            ks[rr][dd] = __bfloat162float(kbase[rr * 64 + dd]);
        }
        __syncthreads();
        float acc[4][4] = {};
        #pragma unroll 8
        for (int dd = 0; dd < 64; dd++) {
            float a[4], b[4];
            #pragma unroll
            for (int i = 0; i < 4; i++) a[i] = qs[ty * 4 + i][dd];
            #pragma unroll
            for (int j = 0; j < 4; j++) b[j] = ks[tx * 4 + j][dd];
            #pragma unroll
            for (int i = 0; i < 4; i++)
                #pragma unroll
                for (int j = 0; j < 4; j++) acc[i][j] += a[i] * b[j];
        }
        #pragma unroll
        for (int i = 0; i < 4; i++) {
            int q = q0 + ty * 4 + i;
            #pragma unroll
            for (int j = 0; j < 4; j++) {
                int k = kt + tx * 4 + j;
                size_t midx = ((size_t)b_ * SS + q) * SS + k;
                int m = maskByte ? (int)mb[midx] : mi[midx];
                float v = m ? -1e9f : acc[i][j] * SCALE_F;
                stf(P, ((size_t)bh * SS + q) * SS + k, v);
            }
        }
        __syncthreads();
    }
}

// ---------- softmax over each row of P (in place) ----------
template <typename T>
__global__ __launch_bounds__(256) void softmax_kernel(const int* __restrict__ flags, int want,
                                                      T* __restrict__ P) {
    if (flags[0] != want) return;
    size_t row = blockIdx.x;
    T* p = P + row * SS;
    int tid = threadIdx.x;
    float vals[8];
    float m = -INFINITY;
    #pragma unroll
    for (int l = 0; l < 8; l++) {
        vals[l] = ldf(p, (size_t)(tid + l * 256));
        m = fmaxf(m, vals[l]);
    }
    __shared__ float red[256];
    red[tid] = m;
    __syncthreads();
    for (int s2 = 128; s2 > 0; s2 >>= 1) {
        if (tid < s2) red[tid] = fmaxf(red[tid], red[tid + s2]);
        __syncthreads();
    }
    m = red[0];
    __syncthreads();
    float sum = 0.0f;
    #pragma unroll
    for (int l = 0; l < 8; l++) {
        vals[l] = __expf(vals[l] - m);
        sum += vals[l];
    }
    red[tid] = sum;
    __syncthreads();
    for (int s2 = 128; s2 > 0; s2 >>= 1) {
        if (tid < s2) red[tid] += red[tid + s2];
        __syncthreads();
    }
    float inv = 1.0f / red[0];
    #pragma unroll
    for (int l = 0; l < 8; l++) stf(p, (size_t)(tid + l * 256), vals[l] * inv);
}

// ---------- context = P @ V, store bf16 ctx [B,S,HID] (heads merged back) ----------
template <typename T>
__global__ __launch_bounds__(256) void context_kernel(const int* __restrict__ flags, int want,
                                                      const T* __restrict__ P,
                                                      const bf16* __restrict__ vh,
                                                      bf16* __restrict__ ctx) {
    if (flags[0] != want) return;
    __shared__ float ps[64][65];
    __shared__ float vs[64][65];
    int tid = threadIdx.x;
    int q0 = blockIdx.x * 64;
    int bh = blockIdx.y;
    int b_ = bh / HH, h = bh % HH;
    int tx = tid & 15, ty = tid >> 4;
    float acc[4][4] = {};
    for (int kt = 0; kt < SS; kt += 64) {
        #pragma unroll
        for (int l = 0; l < 16; l++) {
            int idx = tid + l * 256;
            int rr = idx >> 6, cc = idx & 63;
            ps[rr][cc] = ldf(P, ((size_t)bh * SS + q0 + rr) * SS + kt + cc);
            vs[rr][cc] = __bfloat162float(vh[((size_t)bh * SS + kt + rr) * DD + cc]);
        }
        __syncthreads();
        #pragma unroll 8
        for (int kk = 0; kk < 64; kk++) {
            float a[4], b[4];
            #pragma unroll
            for (int i = 0; i < 4; i++) a[i] = ps[ty * 4 + i][kk];
            #pragma unroll
            for (int j = 0; j < 4; j++) b[j] = vs[kk][tx * 4 + j];
            #pragma unroll
            for (int i = 0; i < 4; i++)
                #pragma unroll
                for (int j = 0; j < 4; j++) acc[i][j] += a[i] * b[j];
        }
        __syncthreads();
    }
    #pragma unroll
    for (int i = 0; i < 4; i++) {
        int q = q0 + ty * 4 + i;
        #pragma unroll
        for (int j = 0; j < 4; j++) {
            int d = tx * 4 + j;
            ctx[((size_t)b_ * SS + q) * HIDD + h * DD + d] = __float2bfloat16(acc[i][j]);
        }
    }
}

// ---------- output projection: out = ctx @ Wo + bo ----------
template <typename T>
__global__ __launch_bounds__(256) void outproj_kernel(const int* __restrict__ flags, int want,
                                                      const bf16* __restrict__ ctx,
                                                      const T* __restrict__ Wo,
                                                      const T* __restrict__ bo,
                                                      T* __restrict__ out) {
    if (flags[0] != want) return;
    __shared__ float xs[64][17];
    __shared__ float wsm[16][65];
    int tid = threadIdx.x;
    int row0 = blockIdx.y * 64;
    int col0 = blockIdx.x * 64;
    int tx = tid & 15, ty = tid >> 4;
    float acc[4][4] = {};
    for (int kt = 0; kt < HIDD; kt += 16) {
        #pragma unroll
        for (int l = 0; l < 4; l++) {
            int idx = tid + l * 256;
            int rr = idx >> 4, kk = idx & 15;
            xs[rr][kk] = __bfloat162float(ctx[(size_t)(row0 + rr) * HIDD + kt + kk]);
        }
        #pragma unroll
        for (int l = 0; l < 4; l++) {
            int idx = tid + l * 256;
            int kk = idx >> 6, cc = idx & 63;
            wsm[kk][cc] = ldf(Wo, (size_t)(kt + kk) * HIDD + col0 + cc);
        }
        __syncthreads();
        #pragma unroll
        for (int kk = 0; kk < 16; kk++) {
            float a[4], b[4];
            #pragma unroll
            for (int i = 0; i < 4; i++) a[i] = xs[ty * 4 + i][kk];
            #pragma unroll
            for (int j = 0; j < 4; j++) b[j] = wsm[kk][tx * 4 + j];
            #pragma unroll
            for (int i = 0; i < 4; i++)
                #pragma unroll
                for (int j = 0; j < 4; j++) acc[i][j] += a[i] * b[j];
        }
        __syncthreads();
    }
    #pragma unroll
    for (int i = 0; i < 4; i++) {
        int r = row0 + ty * 4 + i;
        #pragma unroll
        for (int j = 0; j < 4; j++) {
            int c = col0 + tx * 4 + j;
            stf(out, (size_t)r * HIDD + c, acc[i][j] + ldf(bo, (size_t)c));
        }
    }
}

extern "C" void kernel_launch(void* const* d_in, const int* in_sizes, int n_in,
                              void* d_out, int out_size, void* d_ws, size_t ws_size,
                              hipStream_t stream) {
    const size_t nqkv = (size_t)BB * SS * HIDD;  // 6,291,456

    // workspace layout (all bf16 scratch): qh, kh, vh, ctx then flags
    bf16* qh = (bf16*)d_ws;
    bf16* kh = qh + nqkv;
    bf16* vh = kh + nqkv;
    bf16* ctx = vh + nqkv;
    int* flags = (int*)((char*)d_ws + 4 * nqkv * sizeof(bf16));

    detect_kernel<<<1, 256, 0, stream>>>((const uint32_t*)d_in[0], (const uint32_t*)d_in[3], flags);

    dim3 blk(256);
    dim3 gProj(HIDD / 64, (BB * SS) / 64);   // (12, 128)
    dim3 gAttn(SS / 64, BB * HH);            // (32, 48)
    int nRows = BB * HH * SS;                // 98304 softmax rows

    // ---- fp32 variants (want = 0) ----
    {
        const float* Q = (const float*)d_in[0];
        const float* K = (const float*)d_in[1];
        const float* V = (const float*)d_in[2];
        const float* Wq = (const float*)d_in[4];
        const float* bq = (const float*)d_in[5];
        const float* Wk = (const float*)d_in[6];
        const float* bk = (const float*)d_in[7];
        const float* Wv = (const float*)d_in[8];
        const float* bv = (const float*)d_in[9];
        const float* Wo = (const float*)d_in[10];
        const float* bo = (const float*)d_in[11];
        float* out = (float*)d_out;
        float* P = out + nqkv;
        proj_kernel<float><<<gProj, blk, 0, stream>>>(flags, 0, Q, Wq, bq, qh);
        proj_kernel<float><<<gProj, blk, 0, stream>>>(flags, 0, K, Wk, bk, kh);
        proj_kernel<float><<<gProj, blk, 0, stream>>>(flags, 0, V, Wv, bv, vh);
        scores_kernel<float><<<gAttn, blk, 0, stream>>>(flags, 0, qh, kh, d_in[3], P);
        softmax_kernel<float><<<nRows, blk, 0, stream>>>(flags, 0, P);
        context_kernel<float><<<gAttn, blk, 0, stream>>>(flags, 0, P, vh, ctx);
        outproj_kernel<float><<<gProj, blk, 0, stream>>>(flags, 0, ctx, Wo, bo, out);
    }
    // ---- bf16 variants (want = 1) ----
    {
        const bf16* Q = (const bf16*)d_in[0];
        const bf16* K = (const bf16*)d_in[1];
        const bf16* V = (const bf16*)d_in[2];
        const bf16* Wq = (const bf16*)d_in[4];
        const bf16* bq = (const bf16*)d_in[5];
        const bf16* Wk = (const bf16*)d_in[6];
        const bf16* bk = (const bf16*)d_in[7];
        const bf16* Wv = (const bf16*)d_in[8];
        const bf16* bv = (const bf16*)d_in[9];
        const bf16* Wo = (const bf16*)d_in[10];
        const bf16* bo = (const bf16*)d_in[11];
        bf16* out = (bf16*)d_out;
        bf16* P = out + nqkv;
        proj_kernel<bf16><<<gProj, blk, 0, stream>>>(flags, 1, Q, Wq, bq, qh);
        proj_kernel<bf16><<<gProj, blk, 0, stream>>>(flags, 1, K, Wk, bk, kh);
        proj_kernel<bf16><<<gProj, blk, 0, stream>>>(flags, 1, V, Wv, bv, vh);
        scores_kernel<bf16><<<gAttn, blk, 0, stream>>>(flags, 1, qh, kh, d_in[3], P);
        softmax_kernel<bf16><<<nRows, blk, 0, stream>>>(flags, 1, P);
        context_kernel<bf16><<<gAttn, blk, 0, stream>>>(flags, 1, P, vh, ctx);
        outproj_kernel<bf16><<<gProj, blk, 0, stream>>>(flags, 1, ctx, Wo, bo, out);
    }
}